// Round 1
// baseline (289.104 us; speedup 1.0000x reference)
//
#include <hip/hip_runtime.h>
#include <hip/hip_bf16.h>

typedef __bf16 bf16x8 __attribute__((ext_vector_type(8)));
typedef float  f32x4  __attribute__((ext_vector_type(4)));

#define NEGC (-10000.0f)

// ---------------------------------------------------------------- cvt f32->bf16
__global__ __launch_bounds__(256) void cvt_bf16(const float* __restrict__ in,
                                                __bf16* __restrict__ out, int n8) {
    int i = blockIdx.x * 256 + threadIdx.x;
    if (i >= n8) return;
    f32x4 a = *(const f32x4*)(in + (size_t)i * 8);
    f32x4 b = *(const f32x4*)(in + (size_t)i * 8 + 4);
    bf16x8 o;
    o[0] = (__bf16)a[0]; o[1] = (__bf16)a[1]; o[2] = (__bf16)a[2]; o[3] = (__bf16)a[3];
    o[4] = (__bf16)b[0]; o[5] = (__bf16)b[1]; o[6] = (__bf16)b[2]; o[7] = (__bf16)b[3];
    *(bf16x8*)(out + (size_t)i * 8) = o;
}

// ---------------------------------------------------------------- QKV projection
// out[m][n] = sum_k X[m][k] * W[n][k] + bias[n];  store as [B,H,S,64] bf16
__global__ __launch_bounds__(256) void qkv_gemm(
    const __bf16* __restrict__ X,
    const __bf16* __restrict__ Wq, const __bf16* __restrict__ Wk, const __bf16* __restrict__ Wv,
    const float* __restrict__ bq, const float* __restrict__ bk, const float* __restrict__ bv,
    __bf16* __restrict__ Qo, __bf16* __restrict__ Ko, __bf16* __restrict__ Vo)
{
    const __bf16* W; const float* bias; __bf16* O;
    if (blockIdx.z == 0)      { W = Wq; bias = bq; O = Qo; }
    else if (blockIdx.z == 1) { W = Wk; bias = bk; O = Ko; }
    else                      { W = Wv; bias = bv; O = Vo; }
    int m0 = blockIdx.x * 64, n0 = blockIdx.y * 64;
    int l = threadIdx.x & 63, w = threadIdx.x >> 6;
    int lo = l & 15, hi = l >> 4;

    f32x4 acc[4] = {};
    const __bf16* xp = X + (size_t)(m0 + w * 16 + lo) * 768 + hi * 8;
    const __bf16* wp = W + (size_t)(n0 + lo) * 768 + hi * 8;
    for (int k0 = 0; k0 < 768; k0 += 32) {
        bf16x8 a = *(const bf16x8*)(xp + k0);
#pragma unroll
        for (int nt = 0; nt < 4; nt++) {
            bf16x8 bfr = *(const bf16x8*)(wp + (size_t)nt * 16 * 768 + k0);
            acc[nt] = __builtin_amdgcn_mfma_f32_16x16x32_bf16(a, bfr, acc[nt], 0, 0, 0);
        }
    }
#pragma unroll
    for (int nt = 0; nt < 4; nt++) {
#pragma unroll
        for (int i = 0; i < 4; i++) {
            int m = m0 + w * 16 + hi * 4 + i;
            int n = n0 + nt * 16 + lo;
            float v = acc[nt][i] + bias[n];
            int bb = m >> 10, s = m & 1023, h = n >> 6, d = n & 63;
            O[(size_t)((bb * 12 + h) * 1024 + s) * 64 + d] = (__bf16)v;
        }
    }
}

// ---------------------------------------------------------------- attention
// grid (48, 16): bh, q-block of 64 rows; 4 waves x 16 q-rows
__global__ __launch_bounds__(256) void attn_kernel(
    const __bf16* __restrict__ Q, const __bf16* __restrict__ K, const __bf16* __restrict__ V,
    const float* __restrict__ pmask, float* __restrict__ Pout, __bf16* __restrict__ ctx)
{
    int bh = blockIdx.x;
    int b = bh / 12, h = bh - b * 12;
    int q0 = blockIdx.y * 64;
    int tid = threadIdx.x, l = tid & 63, w = tid >> 6;
    int lo = l & 15, hi = l >> 4;
    int qw = q0 + w * 16;

    const __bf16* Qh = Q + (size_t)bh * 1024 * 64;
    const __bf16* Kh = K + (size_t)bh * 1024 * 64;
    const __bf16* Vh = V + (size_t)bh * 1024 * 64;
    float* Ph = Pout + (size_t)bh * 1024 * 1024;
    const float* pm = pmask + b * 1024;

    __shared__ __align__(16) __bf16 vt[64][40];        // transposed V tile [d][key]
    __shared__ __align__(16) __bf16 plds[4][16][40];   // per-wave P tile [q][key]

    bf16x8 qf0 = *(const bf16x8*)(Qh + (size_t)(qw + lo) * 64 + hi * 8);
    bf16x8 qf1 = *(const bf16x8*)(Qh + (size_t)(qw + lo) * 64 + 32 + hi * 8);

    const float scale = 0.036084391824351615f;  // 1/sqrt(768)
    float mrun[4], lrun[4];
#pragma unroll
    for (int i = 0; i < 4; i++) { mrun[i] = -1e30f; lrun[i] = 0.0f; }

    int ktw = (qw + 15) >> 5;   // last kt this wave needs
    // ---------------- phase 1: row max / sum
    for (int kt = 0; kt <= ktw; kt++) {
        int k0 = kt * 32;
        f32x4 s0 = {}, s1 = {};
        {
            bf16x8 kf0 = *(const bf16x8*)(Kh + (size_t)(k0 + lo) * 64 + hi * 8);
            bf16x8 kf1 = *(const bf16x8*)(Kh + (size_t)(k0 + 16 + lo) * 64 + hi * 8);
            s0 = __builtin_amdgcn_mfma_f32_16x16x32_bf16(qf0, kf0, s0, 0, 0, 0);
            s1 = __builtin_amdgcn_mfma_f32_16x16x32_bf16(qf0, kf1, s1, 0, 0, 0);
            kf0 = *(const bf16x8*)(Kh + (size_t)(k0 + lo) * 64 + 32 + hi * 8);
            kf1 = *(const bf16x8*)(Kh + (size_t)(k0 + 16 + lo) * 64 + 32 + hi * 8);
            s0 = __builtin_amdgcn_mfma_f32_16x16x32_bf16(qf1, kf0, s0, 0, 0, 0);
            s1 = __builtin_amdgcn_mfma_f32_16x16x32_bf16(qf1, kf1, s1, 0, 0, 0);
        }
        int c0 = k0 + lo, c1 = k0 + 16 + lo;
        float pad0 = (1.0f - pm[c0]) * NEGC;
        float pad1 = (1.0f - pm[c1]) * NEGC;
#pragma unroll
        for (int i = 0; i < 4; i++) {
            int r = qw + hi * 4 + i;
            float a0 = s0[i] * scale + pad0; if (c0 > r) a0 = NEGC;
            float a1 = s1[i] * scale + pad1; if (c1 > r) a1 = NEGC;
            float tm = fmaxf(a0, a1);
            tm = fmaxf(tm, __shfl_xor(tm, 1));
            tm = fmaxf(tm, __shfl_xor(tm, 2));
            tm = fmaxf(tm, __shfl_xor(tm, 4));
            tm = fmaxf(tm, __shfl_xor(tm, 8));
            float mnew = fmaxf(mrun[i], tm);
            float ts = __expf(a0 - mnew) + __expf(a1 - mnew);
            ts += __shfl_xor(ts, 1);
            ts += __shfl_xor(ts, 2);
            ts += __shfl_xor(ts, 4);
            ts += __shfl_xor(ts, 8);
            lrun[i] = lrun[i] * __expf(mrun[i] - mnew) + ts;
            mrun[i] = mnew;
        }
    }
    float invl[4];
#pragma unroll
    for (int i = 0; i < 4; i++) invl[i] = 1.0f / lrun[i];

    // ---------------- phase 2: recompute, write P, accumulate PV
    f32x4 cacc[4] = {};
    int ktb = (q0 + 63) >> 5;   // block-uniform bound (barriers inside)
    for (int kt = 0; kt <= ktb; kt++) {
        int k0 = kt * 32;
        {   // stage V[32][64] transposed into vt[d][key]
            int r = tid >> 3, cc = (tid & 7) * 8;
            bf16x8 vv = *(const bf16x8*)(Vh + (size_t)(k0 + r) * 64 + cc);
#pragma unroll
            for (int j = 0; j < 8; j++) vt[cc + j][r] = vv[j];
        }
        __syncthreads();
        float p0[4], p1[4];
        bool act = (kt <= ktw);
        if (act) {
            f32x4 s0 = {}, s1 = {};
            bf16x8 kf0 = *(const bf16x8*)(Kh + (size_t)(k0 + lo) * 64 + hi * 8);
            bf16x8 kf1 = *(const bf16x8*)(Kh + (size_t)(k0 + 16 + lo) * 64 + hi * 8);
            s0 = __builtin_amdgcn_mfma_f32_16x16x32_bf16(qf0, kf0, s0, 0, 0, 0);
            s1 = __builtin_amdgcn_mfma_f32_16x16x32_bf16(qf0, kf1, s1, 0, 0, 0);
            kf0 = *(const bf16x8*)(Kh + (size_t)(k0 + lo) * 64 + 32 + hi * 8);
            kf1 = *(const bf16x8*)(Kh + (size_t)(k0 + 16 + lo) * 64 + 32 + hi * 8);
            s0 = __builtin_amdgcn_mfma_f32_16x16x32_bf16(qf1, kf0, s0, 0, 0, 0);
            s1 = __builtin_amdgcn_mfma_f32_16x16x32_bf16(qf1, kf1, s1, 0, 0, 0);
            int c0 = k0 + lo, c1 = k0 + 16 + lo;
            float pad0 = (1.0f - pm[c0]) * NEGC;
            float pad1 = (1.0f - pm[c1]) * NEGC;
#pragma unroll
            for (int i = 0; i < 4; i++) {
                int r = qw + hi * 4 + i;
                float a0 = s0[i] * scale + pad0; if (c0 > r) a0 = NEGC;
                float a1 = s1[i] * scale + pad1; if (c1 > r) a1 = NEGC;
                p0[i] = __expf(a0 - mrun[i]) * invl[i];   // masked -> exp underflows to 0
                p1[i] = __expf(a1 - mrun[i]) * invl[i];
            }
        } else {
#pragma unroll
            for (int i = 0; i < 4; i++) { p0[i] = 0.0f; p1[i] = 0.0f; }
        }
        // write probs (full coverage incl. zeros; harness poisons d_out)
#pragma unroll
        for (int i = 0; i < 4; i++) {
            float* pr = Ph + (size_t)(qw + hi * 4 + i) * 1024 + k0;
            pr[lo] = p0[i];
            pr[16 + lo] = p1[i];
        }
        // P -> LDS (bf16) for A-fragment repack
#pragma unroll
        for (int i = 0; i < 4; i++) {
            plds[w][hi * 4 + i][lo] = (__bf16)p0[i];
            plds[w][hi * 4 + i][16 + lo] = (__bf16)p1[i];
        }
        if (act) {
            bf16x8 pf = *(const bf16x8*)(&plds[w][lo][hi * 8]);
#pragma unroll
            for (int dt = 0; dt < 4; dt++) {
                bf16x8 vf = *(const bf16x8*)(&vt[dt * 16 + lo][hi * 8]);
                cacc[dt] = __builtin_amdgcn_mfma_f32_16x16x32_bf16(pf, vf, cacc[dt], 0, 0, 0);
            }
        }
        __syncthreads();
    }
    // ctx store: [4096][768] bf16, col = h*64 + d
#pragma unroll
    for (int dt = 0; dt < 4; dt++) {
#pragma unroll
        for (int i = 0; i < 4; i++) {
            int m = b * 1024 + qw + hi * 4 + i;
            int n = h * 64 + dt * 16 + lo;
            ctx[(size_t)m * 768 + n] = (__bf16)cacc[dt][i];
        }
    }
    // zero tail of probs beyond block-causal bound
    for (int c = (ktb + 1) * 32 + lo * 4; c < 1024; c += 64) {
#pragma unroll
        for (int i = 0; i < 4; i++) {
            f32x4 z = {};
            *(f32x4*)(Ph + (size_t)(qw + hi * 4 + i) * 1024 + c) = z;
        }
    }
}

// ---------------------------------------------------------------- out projection + residual
__global__ __launch_bounds__(256) void out_gemm(
    const __bf16* __restrict__ C, const __bf16* __restrict__ Wo,
    const float* __restrict__ bo, const float* __restrict__ emb, float* __restrict__ Y)
{
    int m0 = blockIdx.x * 64, n0 = blockIdx.y * 64;
    int l = threadIdx.x & 63, w = threadIdx.x >> 6;
    int lo = l & 15, hi = l >> 4;

    f32x4 acc[4] = {};
    const __bf16* xp = C + (size_t)(m0 + w * 16 + lo) * 768 + hi * 8;
    const __bf16* wp = Wo + (size_t)(n0 + lo) * 768 + hi * 8;
    for (int k0 = 0; k0 < 768; k0 += 32) {
        bf16x8 a = *(const bf16x8*)(xp + k0);
#pragma unroll
        for (int nt = 0; nt < 4; nt++) {
            bf16x8 bfr = *(const bf16x8*)(wp + (size_t)nt * 16 * 768 + k0);
            acc[nt] = __builtin_amdgcn_mfma_f32_16x16x32_bf16(a, bfr, acc[nt], 0, 0, 0);
        }
    }
#pragma unroll
    for (int nt = 0; nt < 4; nt++) {
#pragma unroll
        for (int i = 0; i < 4; i++) {
            int m = m0 + w * 16 + hi * 4 + i;
            int n = n0 + nt * 16 + lo;
            size_t idx = (size_t)m * 768 + n;
            Y[idx] = acc[nt][i] + bo[n] + emb[idx];
        }
    }
}

// ---------------------------------------------------------------- layernorm (wave per row)
__global__ __launch_bounds__(256) void ln_kernel(
    const float* __restrict__ Y, const float* __restrict__ g, const float* __restrict__ bta,
    float* __restrict__ out)
{
    int row = blockIdx.x * 4 + (threadIdx.x >> 6);
    int l = threadIdx.x & 63;
    const float* yr = Y + (size_t)row * 768;
    f32x4 v0 = *(const f32x4*)(yr + l * 4);
    f32x4 v1 = *(const f32x4*)(yr + 256 + l * 4);
    f32x4 v2 = *(const f32x4*)(yr + 512 + l * 4);
    float s = v0[0] + v0[1] + v0[2] + v0[3] + v1[0] + v1[1] + v1[2] + v1[3]
            + v2[0] + v2[1] + v2[2] + v2[3];
#pragma unroll
    for (int m = 1; m < 64; m <<= 1) s += __shfl_xor(s, m);
    float mu = s * (1.0f / 768.0f);
    float ss = 0.0f;
#pragma unroll
    for (int j = 0; j < 4; j++) {
        float d0 = v0[j] - mu, d1 = v1[j] - mu, d2 = v2[j] - mu;
        ss += d0 * d0 + d1 * d1 + d2 * d2;
    }
#pragma unroll
    for (int m = 1; m < 64; m <<= 1) ss += __shfl_xor(ss, m);
    float r = rsqrtf(ss * (1.0f / 768.0f) + 1e-12f);
    float* orow = out + (size_t)row * 768;
#pragma unroll
    for (int c = 0; c < 3; c++) {
        f32x4 v = (c == 0) ? v0 : ((c == 1) ? v1 : v2);
        int col = c * 256 + l * 4;
        f32x4 gg = *(const f32x4*)(g + col);
        f32x4 bb = *(const f32x4*)(bta + col);
        f32x4 o;
#pragma unroll
        for (int j = 0; j < 4; j++) o[j] = (v[j] - mu) * r * gg[j] + bb[j];
        *(f32x4*)(orow + col) = o;
    }
}

// ---------------------------------------------------------------- launch
extern "C" void kernel_launch(void* const* d_in, const int* in_sizes, int n_in,
                              void* d_out, int out_size, void* d_ws, size_t ws_size,
                              hipStream_t stream)
{
    const float* emb   = (const float*)d_in[0];
    const float* pmask = (const float*)d_in[1];
    const float* wq = (const float*)d_in[2];  const float* bq = (const float*)d_in[3];
    const float* wk = (const float*)d_in[4];  const float* bk = (const float*)d_in[5];
    const float* wv = (const float*)d_in[6];  const float* bv = (const float*)d_in[7];
    const float* wo = (const float*)d_in[8];  const float* bo = (const float*)d_in[9];
    const float* lng = (const float*)d_in[10]; const float* lnb = (const float*)d_in[11];

    __bf16* Xb  = (__bf16*)d_ws;            // 4096*768
    __bf16* Wqb = Xb + 4096 * 768;          // 768*768 each
    __bf16* Wkb = Wqb + 768 * 768;
    __bf16* Wvb = Wkb + 768 * 768;
    __bf16* Wob = Wvb + 768 * 768;
    __bf16* Qb  = Wob + 768 * 768;          // 4*12*1024*64 = 3145728 each
    __bf16* Kb  = Qb + 3145728;
    __bf16* Vb  = Kb + 3145728;
    __bf16* Cb  = Vb + 3145728;
    float*  Yf  = (float*)(Cb + 3145728);   // 4096*768 f32

    float* normed = (float*)d_out;
    float* probs  = normed + (size_t)4096 * 768;

    cvt_bf16<<<1536, 256, 0, stream>>>(emb, Xb, 393216);
    cvt_bf16<<<288, 256, 0, stream>>>(wq, Wqb, 73728);
    cvt_bf16<<<288, 256, 0, stream>>>(wk, Wkb, 73728);
    cvt_bf16<<<288, 256, 0, stream>>>(wv, Wvb, 73728);
    cvt_bf16<<<288, 256, 0, stream>>>(wo, Wob, 73728);

    qkv_gemm<<<dim3(64, 12, 3), 256, 0, stream>>>(Xb, Wqb, Wkb, Wvb, bq, bk, bv, Qb, Kb, Vb);
    attn_kernel<<<dim3(48, 16), 256, 0, stream>>>(Qb, Kb, Vb, pmask, probs, Cb);
    out_gemm<<<dim3(64, 12), 256, 0, stream>>>(Cb, Wob, bo, emb, Yf);
    ln_kernel<<<1024, 256, 0, stream>>>(Yf, lng, lnb, normed);
}

// Round 2
// 181.588 us; speedup vs baseline: 1.5921x; 1.5921x over previous
//
#include <hip/hip_runtime.h>
#include <hip/hip_bf16.h>

typedef __bf16 bf16x8 __attribute__((ext_vector_type(8)));
typedef float  f32x4  __attribute__((ext_vector_type(4)));

#define NEGC (-10000.0f)

// ---------------------------------------------------------------- cvt f32->bf16 (embeddings)
__global__ __launch_bounds__(256) void cvt_bf16(const float* __restrict__ in,
                                                __bf16* __restrict__ out, int n8) {
    int i = blockIdx.x * 256 + threadIdx.x;
    if (i >= n8) return;
    f32x4 a = *(const f32x4*)(in + (size_t)i * 8);
    f32x4 b = *(const f32x4*)(in + (size_t)i * 8 + 4);
    bf16x8 o;
    o[0] = (__bf16)a[0]; o[1] = (__bf16)a[1]; o[2] = (__bf16)a[2]; o[3] = (__bf16)a[3];
    o[4] = (__bf16)b[0]; o[5] = (__bf16)b[1]; o[6] = (__bf16)b[2]; o[7] = (__bf16)b[3];
    *(bf16x8*)(out + (size_t)i * 8) = o;
}

// ---------------------------------------------------------------- cvt all 4 weight matrices
// dst: [q|k|v|o] each 768*768 bf16, contiguous. 288 blocks per weight.
__global__ __launch_bounds__(256) void cvt_w4(const float* __restrict__ q, const float* __restrict__ k,
                                              const float* __restrict__ v, const float* __restrict__ o,
                                              __bf16* __restrict__ dst) {
    int blk = blockIdx.x;
    int which = blk / 288;
    const float* src = which == 0 ? q : which == 1 ? k : which == 2 ? v : o;
    int i = (blk - which * 288) * 256 + threadIdx.x;   // 288*256 == 73728 exactly
    f32x4 a = *(const f32x4*)(src + (size_t)i * 8);
    f32x4 b = *(const f32x4*)(src + (size_t)i * 8 + 4);
    bf16x8 o8;
    o8[0] = (__bf16)a[0]; o8[1] = (__bf16)a[1]; o8[2] = (__bf16)a[2]; o8[3] = (__bf16)a[3];
    o8[4] = (__bf16)b[0]; o8[5] = (__bf16)b[1]; o8[6] = (__bf16)b[2]; o8[7] = (__bf16)b[3];
    *(bf16x8*)(dst + (size_t)which * 589824 + (size_t)i * 8) = o8;
}

// ---------------------------------------------------------------- m97-structure GEMM
// C[m][n] = sum_k A[m][k] * Bw[n][k]   (A: [M][768] bf16, Bw: [N][768] bf16 row-major)
// 128x128 tile, BK=32, 4 waves (2x2), each wave 64x64 = 4x4 fragments of 16x16x32.
// Staging: global_load_lds width=16, linear LDS [128][32].
// MODE 0: fused QKV epilogue -> Q/K/V [B,H,S,64] bf16 with per-slice bias.
// MODE 1: out-proj epilogue  -> Yout[m*768+n] = acc + bias[n] + res[m*768+n] (f32).
template<int MODE>
__global__ __launch_bounds__(256) void gemm128(
    const __bf16* __restrict__ A, const __bf16* __restrict__ Bw,
    const float* __restrict__ b0, const float* __restrict__ b1, const float* __restrict__ b2,
    __bf16* __restrict__ O0, __bf16* __restrict__ O1, __bf16* __restrict__ O2,
    const float* __restrict__ res, float* __restrict__ Yout)
{
    __shared__ __align__(16) __bf16 As[128 * 32];
    __shared__ __align__(16) __bf16 Bs[128 * 32];
    const int K = 768;
    int tid = threadIdx.x;
    int l = tid & 63, w = tid >> 6;
    int lo = l & 15, hi = l >> 4;
    int m0 = blockIdx.x * 128, n0 = blockIdx.y * 128;
    int wr = w >> 1, wc = w & 1;

    f32x4 acc[4][4] = {};

    // staging map: issue i (rows +0 / +64), wave w rows w*16+(l>>2), col (l&3)*8
    int srow = w * 16 + (l >> 2);
    int scol = (l & 3) * 8;
    const __bf16* gA = A + (size_t)(m0 + srow) * K + scol;
    const __bf16* gB = Bw + (size_t)(n0 + srow) * K + scol;
    __bf16* lA = As + w * 512 + l * 8;     // byte off = w*1024 + l*16 (linear, lane-ordered)
    __bf16* lB = Bs + w * 512 + l * 8;

    for (int k0 = 0; k0 < K; k0 += 32) {
        if (k0) __syncthreads();
        __builtin_amdgcn_global_load_lds((const __attribute__((address_space(1))) unsigned int*)(gA + k0),
                                         (__attribute__((address_space(3))) unsigned int*)lA, 16, 0, 0);
        __builtin_amdgcn_global_load_lds((const __attribute__((address_space(1))) unsigned int*)(gA + (size_t)64 * K + k0),
                                         (__attribute__((address_space(3))) unsigned int*)(lA + 2048), 16, 0, 0);
        __builtin_amdgcn_global_load_lds((const __attribute__((address_space(1))) unsigned int*)(gB + k0),
                                         (__attribute__((address_space(3))) unsigned int*)lB, 16, 0, 0);
        __builtin_amdgcn_global_load_lds((const __attribute__((address_space(1))) unsigned int*)(gB + (size_t)64 * K + k0),
                                         (__attribute__((address_space(3))) unsigned int*)(lB + 2048), 16, 0, 0);
        __syncthreads();   // drains vmcnt(0): staged tile visible

        bf16x8 af[4], bfr[4];
#pragma unroll
        for (int mi = 0; mi < 4; mi++)
            af[mi] = *(const bf16x8*)(As + (wr * 64 + mi * 16 + lo) * 32 + hi * 8);
#pragma unroll
        for (int ni = 0; ni < 4; ni++)
            bfr[ni] = *(const bf16x8*)(Bs + (wc * 64 + ni * 16 + lo) * 32 + hi * 8);
#pragma unroll
        for (int mi = 0; mi < 4; mi++)
#pragma unroll
            for (int ni = 0; ni < 4; ni++)
                acc[mi][ni] = __builtin_amdgcn_mfma_f32_16x16x32_bf16(af[mi], bfr[ni], acc[mi][ni], 0, 0, 0);
    }

    if constexpr (MODE == 0) {
        int which = n0 / 768;                       // block-uniform (128 | 768)
        const float* bias = which == 0 ? b0 : (which == 1 ? b1 : b2);
        __bf16* O = which == 0 ? O0 : (which == 1 ? O1 : O2);
        int nbase = n0 - which * 768;
#pragma unroll
        for (int mi = 0; mi < 4; mi++)
#pragma unroll
            for (int ni = 0; ni < 4; ni++) {
                int within = nbase + wc * 64 + ni * 16 + lo;
                float bv = bias[within];
                int h = within >> 6, d = within & 63;
#pragma unroll
                for (int i = 0; i < 4; i++) {
                    int m = m0 + wr * 64 + mi * 16 + hi * 4 + i;
                    int bb = m >> 10, s = m & 1023;
                    O[(size_t)((bb * 12 + h) * 1024 + s) * 64 + d] = (__bf16)(acc[mi][ni][i] + bv);
                }
            }
    } else {
#pragma unroll
        for (int mi = 0; mi < 4; mi++)
#pragma unroll
            for (int ni = 0; ni < 4; ni++) {
                int n = n0 + wc * 64 + ni * 16 + lo;
                float bv = b0[n];
#pragma unroll
                for (int i = 0; i < 4; i++) {
                    int m = m0 + wr * 64 + mi * 16 + hi * 4 + i;
                    size_t idx = (size_t)m * 768 + n;
                    Yout[idx] = acc[mi][ni][i] + bv + res[idx];
                }
            }
    }
}

// ---------------------------------------------------------------- attention (unchanged, known-correct)
// grid (48, 16): bh, q-block of 64 rows; 4 waves x 16 q-rows
__global__ __launch_bounds__(256) void attn_kernel(
    const __bf16* __restrict__ Q, const __bf16* __restrict__ K, const __bf16* __restrict__ V,
    const float* __restrict__ pmask, float* __restrict__ Pout, __bf16* __restrict__ ctx)
{
    int bh = blockIdx.x;
    int b = bh / 12, h = bh - b * 12;
    int q0 = blockIdx.y * 64;
    int tid = threadIdx.x, l = tid & 63, w = tid >> 6;
    int lo = l & 15, hi = l >> 4;
    int qw = q0 + w * 16;

    const __bf16* Qh = Q + (size_t)bh * 1024 * 64;
    const __bf16* Kh = K + (size_t)bh * 1024 * 64;
    const __bf16* Vh = V + (size_t)bh * 1024 * 64;
    float* Ph = Pout + (size_t)bh * 1024 * 1024;
    const float* pm = pmask + b * 1024;

    __shared__ __align__(16) __bf16 vt[64][40];        // transposed V tile [d][key]
    __shared__ __align__(16) __bf16 plds[4][16][40];   // per-wave P tile [q][key]

    bf16x8 qf0 = *(const bf16x8*)(Qh + (size_t)(qw + lo) * 64 + hi * 8);
    bf16x8 qf1 = *(const bf16x8*)(Qh + (size_t)(qw + lo) * 64 + 32 + hi * 8);

    const float scale = 0.036084391824351615f;  // 1/sqrt(768)
    float mrun[4], lrun[4];
#pragma unroll
    for (int i = 0; i < 4; i++) { mrun[i] = -1e30f; lrun[i] = 0.0f; }

    int ktw = (qw + 15) >> 5;   // last kt this wave needs
    // ---------------- phase 1: row max / sum
    for (int kt = 0; kt <= ktw; kt++) {
        int k0 = kt * 32;
        f32x4 s0 = {}, s1 = {};
        {
            bf16x8 kf0 = *(const bf16x8*)(Kh + (size_t)(k0 + lo) * 64 + hi * 8);
            bf16x8 kf1 = *(const bf16x8*)(Kh + (size_t)(k0 + 16 + lo) * 64 + hi * 8);
            s0 = __builtin_amdgcn_mfma_f32_16x16x32_bf16(qf0, kf0, s0, 0, 0, 0);
            s1 = __builtin_amdgcn_mfma_f32_16x16x32_bf16(qf0, kf1, s1, 0, 0, 0);
            kf0 = *(const bf16x8*)(Kh + (size_t)(k0 + lo) * 64 + 32 + hi * 8);
            kf1 = *(const bf16x8*)(Kh + (size_t)(k0 + 16 + lo) * 64 + 32 + hi * 8);
            s0 = __builtin_amdgcn_mfma_f32_16x16x32_bf16(qf1, kf0, s0, 0, 0, 0);
            s1 = __builtin_amdgcn_mfma_f32_16x16x32_bf16(qf1, kf1, s1, 0, 0, 0);
        }
        int c0 = k0 + lo, c1 = k0 + 16 + lo;
        float pad0 = (1.0f - pm[c0]) * NEGC;
        float pad1 = (1.0f - pm[c1]) * NEGC;
#pragma unroll
        for (int i = 0; i < 4; i++) {
            int r = qw + hi * 4 + i;
            float a0 = s0[i] * scale + pad0; if (c0 > r) a0 = NEGC;
            float a1 = s1[i] * scale + pad1; if (c1 > r) a1 = NEGC;
            float tm = fmaxf(a0, a1);
            tm = fmaxf(tm, __shfl_xor(tm, 1));
            tm = fmaxf(tm, __shfl_xor(tm, 2));
            tm = fmaxf(tm, __shfl_xor(tm, 4));
            tm = fmaxf(tm, __shfl_xor(tm, 8));
            float mnew = fmaxf(mrun[i], tm);
            float ts = __expf(a0 - mnew) + __expf(a1 - mnew);
            ts += __shfl_xor(ts, 1);
            ts += __shfl_xor(ts, 2);
            ts += __shfl_xor(ts, 4);
            ts += __shfl_xor(ts, 8);
            lrun[i] = lrun[i] * __expf(mrun[i] - mnew) + ts;
            mrun[i] = mnew;
        }
    }
    float invl[4];
#pragma unroll
    for (int i = 0; i < 4; i++) invl[i] = 1.0f / lrun[i];

    // ---------------- phase 2: recompute, write P, accumulate PV
    f32x4 cacc[4] = {};
    int ktb = (q0 + 63) >> 5;   // block-uniform bound (barriers inside)
    for (int kt = 0; kt <= ktb; kt++) {
        int k0 = kt * 32;
        {   // stage V[32][64] transposed into vt[d][key]
            int r = tid >> 3, cc = (tid & 7) * 8;
            bf16x8 vv = *(const bf16x8*)(Vh + (size_t)(k0 + r) * 64 + cc);
#pragma unroll
            for (int j = 0; j < 8; j++) vt[cc + j][r] = vv[j];
        }
        __syncthreads();
        float p0[4], p1[4];
        bool act = (kt <= ktw);
        if (act) {
            f32x4 s0 = {}, s1 = {};
            bf16x8 kf0 = *(const bf16x8*)(Kh + (size_t)(k0 + lo) * 64 + hi * 8);
            bf16x8 kf1 = *(const bf16x8*)(Kh + (size_t)(k0 + 16 + lo) * 64 + hi * 8);
            s0 = __builtin_amdgcn_mfma_f32_16x16x32_bf16(qf0, kf0, s0, 0, 0, 0);
            s1 = __builtin_amdgcn_mfma_f32_16x16x32_bf16(qf0, kf1, s1, 0, 0, 0);
            kf0 = *(const bf16x8*)(Kh + (size_t)(k0 + lo) * 64 + 32 + hi * 8);
            kf1 = *(const bf16x8*)(Kh + (size_t)(k0 + 16 + lo) * 64 + 32 + hi * 8);
            s0 = __builtin_amdgcn_mfma_f32_16x16x32_bf16(qf1, kf0, s0, 0, 0, 0);
            s1 = __builtin_amdgcn_mfma_f32_16x16x32_bf16(qf1, kf1, s1, 0, 0, 0);
            int c0 = k0 + lo, c1 = k0 + 16 + lo;
            float pad0 = (1.0f - pm[c0]) * NEGC;
            float pad1 = (1.0f - pm[c1]) * NEGC;
#pragma unroll
            for (int i = 0; i < 4; i++) {
                int r = qw + hi * 4 + i;
                float a0 = s0[i] * scale + pad0; if (c0 > r) a0 = NEGC;
                float a1 = s1[i] * scale + pad1; if (c1 > r) a1 = NEGC;
                p0[i] = __expf(a0 - mrun[i]) * invl[i];
                p1[i] = __expf(a1 - mrun[i]) * invl[i];
            }
        } else {
#pragma unroll
            for (int i = 0; i < 4; i++) { p0[i] = 0.0f; p1[i] = 0.0f; }
        }
        // write probs (full coverage incl. zeros; harness poisons d_out)
#pragma unroll
        for (int i = 0; i < 4; i++) {
            float* pr = Ph + (size_t)(qw + hi * 4 + i) * 1024 + k0;
            pr[lo] = p0[i];
            pr[16 + lo] = p1[i];
        }
#pragma unroll
        for (int i = 0; i < 4; i++) {
            plds[w][hi * 4 + i][lo] = (__bf16)p0[i];
            plds[w][hi * 4 + i][16 + lo] = (__bf16)p1[i];
        }
        if (act) {
            bf16x8 pf = *(const bf16x8*)(&plds[w][lo][hi * 8]);
#pragma unroll
            for (int dt = 0; dt < 4; dt++) {
                bf16x8 vf = *(const bf16x8*)(&vt[dt * 16 + lo][hi * 8]);
                cacc[dt] = __builtin_amdgcn_mfma_f32_16x16x32_bf16(pf, vf, cacc[dt], 0, 0, 0);
            }
        }
        __syncthreads();
    }
    // ctx store: [4096][768] bf16, col = h*64 + d
#pragma unroll
    for (int dt = 0; dt < 4; dt++) {
#pragma unroll
        for (int i = 0; i < 4; i++) {
            int m = b * 1024 + qw + hi * 4 + i;
            int n = h * 64 + dt * 16 + lo;
            ctx[(size_t)m * 768 + n] = (__bf16)cacc[dt][i];
        }
    }
    // zero tail of probs beyond block-causal bound
    for (int c = (ktb + 1) * 32 + lo * 4; c < 1024; c += 64) {
#pragma unroll
        for (int i = 0; i < 4; i++) {
            f32x4 z = {};
            *(f32x4*)(Ph + (size_t)(qw + hi * 4 + i) * 1024 + c) = z;
        }
    }
}

// ---------------------------------------------------------------- layernorm (wave per row)
__global__ __launch_bounds__(256) void ln_kernel(
    const float* __restrict__ Y, const float* __restrict__ g, const float* __restrict__ bta,
    float* __restrict__ out)
{
    int row = blockIdx.x * 4 + (threadIdx.x >> 6);
    int l = threadIdx.x & 63;
    const float* yr = Y + (size_t)row * 768;
    f32x4 v0 = *(const f32x4*)(yr + l * 4);
    f32x4 v1 = *(const f32x4*)(yr + 256 + l * 4);
    f32x4 v2 = *(const f32x4*)(yr + 512 + l * 4);
    float s = v0[0] + v0[1] + v0[2] + v0[3] + v1[0] + v1[1] + v1[2] + v1[3]
            + v2[0] + v2[1] + v2[2] + v2[3];
#pragma unroll
    for (int m = 1; m < 64; m <<= 1) s += __shfl_xor(s, m);
    float mu = s * (1.0f / 768.0f);
    float ss = 0.0f;
#pragma unroll
    for (int j = 0; j < 4; j++) {
        float d0 = v0[j] - mu, d1 = v1[j] - mu, d2 = v2[j] - mu;
        ss += d0 * d0 + d1 * d1 + d2 * d2;
    }
#pragma unroll
    for (int m = 1; m < 64; m <<= 1) ss += __shfl_xor(ss, m);
    float r = rsqrtf(ss * (1.0f / 768.0f) + 1e-12f);
    float* orow = out + (size_t)row * 768;
#pragma unroll
    for (int c = 0; c < 3; c++) {
        f32x4 v = (c == 0) ? v0 : ((c == 1) ? v1 : v2);
        int col = c * 256 + l * 4;
        f32x4 gg = *(const f32x4*)(g + col);
        f32x4 bb = *(const f32x4*)(bta + col);
        f32x4 o;
#pragma unroll
        for (int j = 0; j < 4; j++) o[j] = (v[j] - mu) * r * gg[j] + bb[j];
        *(f32x4*)(orow + col) = o;
    }
}

// ---------------------------------------------------------------- launch
extern "C" void kernel_launch(void* const* d_in, const int* in_sizes, int n_in,
                              void* d_out, int out_size, void* d_ws, size_t ws_size,
                              hipStream_t stream)
{
    const float* emb   = (const float*)d_in[0];
    const float* pmask = (const float*)d_in[1];
    const float* wq = (const float*)d_in[2];  const float* bq = (const float*)d_in[3];
    const float* wk = (const float*)d_in[4];  const float* bk = (const float*)d_in[5];
    const float* wv = (const float*)d_in[6];  const float* bv = (const float*)d_in[7];
    const float* wo = (const float*)d_in[8];  const float* bo = (const float*)d_in[9];
    const float* lng = (const float*)d_in[10]; const float* lnb = (const float*)d_in[11];

    __bf16* Xb   = (__bf16*)d_ws;            // 4096*768
    __bf16* Wall = Xb + 4096 * 768;          // 4*768*768  [Wq|Wk|Wv|Wo]
    __bf16* Qb   = Wall + 4 * 589824;        // 4*12*1024*64 each
    __bf16* Kb   = Qb + 3145728;
    __bf16* Vb   = Kb + 3145728;
    __bf16* Cb   = Vb + 3145728;
    float*  Yf   = (float*)(Cb + 3145728);   // 4096*768 f32

    float* normed = (float*)d_out;
    float* probs  = normed + (size_t)4096 * 768;

    cvt_bf16<<<1536, 256, 0, stream>>>(emb, Xb, 393216);
    cvt_w4<<<1152, 256, 0, stream>>>(wq, wk, wv, wo, Wall);

    // fused QKV: A=[4096][768], Bw=[2304][768] (q,k,v rows concatenated)
    gemm128<0><<<dim3(32, 18), 256, 0, stream>>>(Xb, Wall, bq, bk, bv, Qb, Kb, Vb, nullptr, nullptr);
    attn_kernel<<<dim3(48, 16), 256, 0, stream>>>(Qb, Kb, Vb, pmask, probs, Cb);
    // out-proj + bias + residual
    gemm128<1><<<dim3(32, 6), 256, 0, stream>>>(Cb, Wall + 3 * 589824, bo, nullptr, nullptr,
                                                nullptr, nullptr, nullptr, emb, Yf);
    ln_kernel<<<1024, 256, 0, stream>>>(Yf, lng, lnb, normed);
}

// Round 3
// 164.003 us; speedup vs baseline: 1.7628x; 1.1072x over previous
//
#include <hip/hip_runtime.h>
#include <hip/hip_bf16.h>

typedef __bf16 bf16x8 __attribute__((ext_vector_type(8)));
typedef float  f32x4  __attribute__((ext_vector_type(4)));

#define NEGC (-10000.0f)

// ---------------------------------------------------------------- cvt f32->bf16 (embeddings)
__global__ __launch_bounds__(256) void cvt_bf16(const float* __restrict__ in,
                                                __bf16* __restrict__ out, int n8) {
    int i = blockIdx.x * 256 + threadIdx.x;
    if (i >= n8) return;
    f32x4 a = *(const f32x4*)(in + (size_t)i * 8);
    f32x4 b = *(const f32x4*)(in + (size_t)i * 8 + 4);
    bf16x8 o;
    o[0] = (__bf16)a[0]; o[1] = (__bf16)a[1]; o[2] = (__bf16)a[2]; o[3] = (__bf16)a[3];
    o[4] = (__bf16)b[0]; o[5] = (__bf16)b[1]; o[6] = (__bf16)b[2]; o[7] = (__bf16)b[3];
    *(bf16x8*)(out + (size_t)i * 8) = o;
}

// ---------------------------------------------------------------- cvt all 4 weight matrices
__global__ __launch_bounds__(256) void cvt_w4(const float* __restrict__ q, const float* __restrict__ k,
                                              const float* __restrict__ v, const float* __restrict__ o,
                                              __bf16* __restrict__ dst) {
    int blk = blockIdx.x;
    int which = blk / 288;
    const float* src = which == 0 ? q : which == 1 ? k : which == 2 ? v : o;
    int i = (blk - which * 288) * 256 + threadIdx.x;
    f32x4 a = *(const f32x4*)(src + (size_t)i * 8);
    f32x4 b = *(const f32x4*)(src + (size_t)i * 8 + 4);
    bf16x8 o8;
    o8[0] = (__bf16)a[0]; o8[1] = (__bf16)a[1]; o8[2] = (__bf16)a[2]; o8[3] = (__bf16)a[3];
    o8[4] = (__bf16)b[0]; o8[5] = (__bf16)b[1]; o8[6] = (__bf16)b[2]; o8[7] = (__bf16)b[3];
    *(bf16x8*)(dst + (size_t)which * 589824 + (size_t)i * 8) = o8;
}

// ---------------------------------------------------------------- m97-structure GEMM (unchanged)
template<int MODE>
__global__ __launch_bounds__(256) void gemm128(
    const __bf16* __restrict__ A, const __bf16* __restrict__ Bw,
    const float* __restrict__ b0, const float* __restrict__ b1, const float* __restrict__ b2,
    __bf16* __restrict__ O0, __bf16* __restrict__ O1, __bf16* __restrict__ O2,
    const float* __restrict__ res, float* __restrict__ Yout)
{
    __shared__ __align__(16) __bf16 As[128 * 32];
    __shared__ __align__(16) __bf16 Bs[128 * 32];
    const int K = 768;
    int tid = threadIdx.x;
    int l = tid & 63, w = tid >> 6;
    int lo = l & 15, hi = l >> 4;
    int m0 = blockIdx.x * 128, n0 = blockIdx.y * 128;
    int wr = w >> 1, wc = w & 1;

    f32x4 acc[4][4] = {};

    int srow = w * 16 + (l >> 2);
    int scol = (l & 3) * 8;
    const __bf16* gA = A + (size_t)(m0 + srow) * K + scol;
    const __bf16* gB = Bw + (size_t)(n0 + srow) * K + scol;
    __bf16* lA = As + w * 512 + l * 8;
    __bf16* lB = Bs + w * 512 + l * 8;

    for (int k0 = 0; k0 < K; k0 += 32) {
        if (k0) __syncthreads();
        __builtin_amdgcn_global_load_lds((const __attribute__((address_space(1))) unsigned int*)(gA + k0),
                                         (__attribute__((address_space(3))) unsigned int*)lA, 16, 0, 0);
        __builtin_amdgcn_global_load_lds((const __attribute__((address_space(1))) unsigned int*)(gA + (size_t)64 * K + k0),
                                         (__attribute__((address_space(3))) unsigned int*)(lA + 2048), 16, 0, 0);
        __builtin_amdgcn_global_load_lds((const __attribute__((address_space(1))) unsigned int*)(gB + k0),
                                         (__attribute__((address_space(3))) unsigned int*)lB, 16, 0, 0);
        __builtin_amdgcn_global_load_lds((const __attribute__((address_space(1))) unsigned int*)(gB + (size_t)64 * K + k0),
                                         (__attribute__((address_space(3))) unsigned int*)(lB + 2048), 16, 0, 0);
        __syncthreads();

        bf16x8 af[4], bfr[4];
#pragma unroll
        for (int mi = 0; mi < 4; mi++)
            af[mi] = *(const bf16x8*)(As + (wr * 64 + mi * 16 + lo) * 32 + hi * 8);
#pragma unroll
        for (int ni = 0; ni < 4; ni++)
            bfr[ni] = *(const bf16x8*)(Bs + (wc * 64 + ni * 16 + lo) * 32 + hi * 8);
#pragma unroll
        for (int mi = 0; mi < 4; mi++)
#pragma unroll
            for (int ni = 0; ni < 4; ni++)
                acc[mi][ni] = __builtin_amdgcn_mfma_f32_16x16x32_bf16(af[mi], bfr[ni], acc[mi][ni], 0, 0, 0);
    }

    if constexpr (MODE == 0) {
        int which = n0 / 768;
        const float* bias = which == 0 ? b0 : (which == 1 ? b1 : b2);
        __bf16* O = which == 0 ? O0 : (which == 1 ? O1 : O2);
        int nbase = n0 - which * 768;
#pragma unroll
        for (int mi = 0; mi < 4; mi++)
#pragma unroll
            for (int ni = 0; ni < 4; ni++) {
                int within = nbase + wc * 64 + ni * 16 + lo;
                float bv = bias[within];
                int h = within >> 6, d = within & 63;
#pragma unroll
                for (int i = 0; i < 4; i++) {
                    int m = m0 + wr * 64 + mi * 16 + hi * 4 + i;
                    int bb = m >> 10, s = m & 1023;
                    O[(size_t)((bb * 12 + h) * 1024 + s) * 64 + d] = (__bf16)(acc[mi][ni][i] + bv);
                }
            }
    } else {
#pragma unroll
        for (int mi = 0; mi < 4; mi++)
#pragma unroll
            for (int ni = 0; ni < 4; ni++) {
                int n = n0 + wc * 64 + ni * 16 + lo;
                float bv = b0[n];
#pragma unroll
                for (int i = 0; i < 4; i++) {
                    int m = m0 + wr * 64 + mi * 16 + hi * 4 + i;
                    size_t idx = (size_t)m * 768 + n;
                    Yout[idx] = acc[mi][ni][i] + bv + res[idx];
                }
            }
    }
}

// ---------------------------------------------------------------- attention v2
// No-max softmax (logits provably bounded ~|5| << 87): pass A computes
// unnormalized E=exp(a), per-lane row sums, and E*V (normalize ctx at end).
// Pass B recomputes E, scales by 1/l, writes P. No cross-lane ops in loops.
__global__ __launch_bounds__(256) void attn_kernel(
    const __bf16* __restrict__ Q, const __bf16* __restrict__ K, const __bf16* __restrict__ V,
    const float* __restrict__ pmask, float* __restrict__ Pout, __bf16* __restrict__ ctx)
{
    int bh = blockIdx.x;
    int b = bh / 12, h = bh - b * 12;
    int q0 = blockIdx.y * 64;
    int tid = threadIdx.x, l = tid & 63, w = tid >> 6;
    int lo = l & 15, hi = l >> 4;
    int qw = q0 + w * 16;

    const __bf16* Qh = Q + (size_t)bh * 65536;
    const __bf16* Kh = K + (size_t)bh * 65536;
    const __bf16* Vh = V + (size_t)bh * 65536;
    float* Ph = Pout + (size_t)bh * 1048576;
    const float* pm = pmask + b * 1024;

    __shared__ __align__(16) __bf16 vt[2][64][40];     // double-buffered V^T tile [d][key]
    __shared__ __align__(16) __bf16 plds[4][16][40];   // per-wave E tile [q][key]

    bf16x8 qf0 = *(const bf16x8*)(Qh + (size_t)(qw + lo) * 64 + hi * 8);
    bf16x8 qf1 = *(const bf16x8*)(Qh + (size_t)(qw + lo) * 64 + 32 + hi * 8);

    const float scale = 0.036084391824351615f;  // 1/sqrt(768)
    int ktw = (qw + 15) >> 5;   // last kt this wave needs
    int ktb = (q0 + 63) >> 5;   // block-uniform bound

    float lsum[4] = {};
    f32x4 cacc[4] = {};

    // stage tile 0
    {
        int r = tid & 31, cc = ((tid >> 5) & 7) * 8;
        bf16x8 vv = *(const bf16x8*)(Vh + (size_t)r * 64 + cc);
#pragma unroll
        for (int j = 0; j < 8; j++) vt[0][cc + j][r] = vv[j];
    }
    __syncthreads();

    // ---------------- pass A: E, row sums, E*V (1 barrier per kt)
    for (int kt = 0; kt <= ktb; kt++) {
        int cur = kt & 1;
        if (kt < ktb) {   // prefetch next V tile into other buffer
            int r = tid & 31, cc = ((tid >> 5) & 7) * 8;
            bf16x8 vv = *(const bf16x8*)(Vh + (size_t)((kt + 1) * 32 + r) * 64 + cc);
#pragma unroll
            for (int j = 0; j < 8; j++) vt[cur ^ 1][cc + j][r] = vv[j];
        }
        if (kt <= ktw) {
            int k0 = kt * 32;
            f32x4 s0 = {}, s1 = {};
            {
                bf16x8 kf0 = *(const bf16x8*)(Kh + (size_t)(k0 + lo) * 64 + hi * 8);
                bf16x8 kf1 = *(const bf16x8*)(Kh + (size_t)(k0 + 16 + lo) * 64 + hi * 8);
                s0 = __builtin_amdgcn_mfma_f32_16x16x32_bf16(qf0, kf0, s0, 0, 0, 0);
                s1 = __builtin_amdgcn_mfma_f32_16x16x32_bf16(qf0, kf1, s1, 0, 0, 0);
                kf0 = *(const bf16x8*)(Kh + (size_t)(k0 + lo) * 64 + 32 + hi * 8);
                kf1 = *(const bf16x8*)(Kh + (size_t)(k0 + 16 + lo) * 64 + 32 + hi * 8);
                s0 = __builtin_amdgcn_mfma_f32_16x16x32_bf16(qf1, kf0, s0, 0, 0, 0);
                s1 = __builtin_amdgcn_mfma_f32_16x16x32_bf16(qf1, kf1, s1, 0, 0, 0);
            }
            int c0 = k0 + lo, c1 = k0 + 16 + lo;
            float pad0 = (1.0f - pm[c0]) * NEGC;
            float pad1 = (1.0f - pm[c1]) * NEGC;
#pragma unroll
            for (int i = 0; i < 4; i++) {
                int r = qw + hi * 4 + i;
                float a0 = s0[i] * scale + pad0; if (c0 > r) a0 = NEGC;
                float a1 = s1[i] * scale + pad1; if (c1 > r) a1 = NEGC;
                float e0 = __expf(a0), e1 = __expf(a1);   // masked -> exactly 0
                lsum[i] += e0 + e1;
                plds[w][hi * 4 + i][lo] = (__bf16)e0;
                plds[w][hi * 4 + i][16 + lo] = (__bf16)e1;
            }
            bf16x8 pf = *(const bf16x8*)(&plds[w][lo][hi * 8]);
#pragma unroll
            for (int dt = 0; dt < 4; dt++) {
                bf16x8 vf = *(const bf16x8*)(&vt[cur][dt * 16 + lo][hi * 8]);
                cacc[dt] = __builtin_amdgcn_mfma_f32_16x16x32_bf16(pf, vf, cacc[dt], 0, 0, 0);
            }
        }
        __syncthreads();
    }

    // one-time row-sum reduction (lanes sharing hi hold same rows, cols in lo)
    float invl[4];
#pragma unroll
    for (int i = 0; i < 4; i++) {
        float s = lsum[i];
        s += __shfl_xor(s, 1);
        s += __shfl_xor(s, 2);
        s += __shfl_xor(s, 4);
        s += __shfl_xor(s, 8);
        invl[i] = 1.0f / s;
    }

    // ctx store (normalized): [4096][768] bf16, col = h*64 + d
#pragma unroll
    for (int dt = 0; dt < 4; dt++) {
#pragma unroll
        for (int i = 0; i < 4; i++) {
            int m = b * 1024 + qw + hi * 4 + i;
            int n = h * 64 + dt * 16 + lo;
            ctx[(size_t)m * 768 + n] = (__bf16)(cacc[dt][i] * invl[i]);
        }
    }

    // ---------------- pass B: recompute E, write normalized P (barrier-free)
    for (int kt = 0; kt <= ktw; kt++) {
        int k0 = kt * 32;
        f32x4 s0 = {}, s1 = {};
        {
            bf16x8 kf0 = *(const bf16x8*)(Kh + (size_t)(k0 + lo) * 64 + hi * 8);
            bf16x8 kf1 = *(const bf16x8*)(Kh + (size_t)(k0 + 16 + lo) * 64 + hi * 8);
            s0 = __builtin_amdgcn_mfma_f32_16x16x32_bf16(qf0, kf0, s0, 0, 0, 0);
            s1 = __builtin_amdgcn_mfma_f32_16x16x32_bf16(qf0, kf1, s1, 0, 0, 0);
            kf0 = *(const bf16x8*)(Kh + (size_t)(k0 + lo) * 64 + 32 + hi * 8);
            kf1 = *(const bf16x8*)(Kh + (size_t)(k0 + 16 + lo) * 64 + 32 + hi * 8);
            s0 = __builtin_amdgcn_mfma_f32_16x16x32_bf16(qf1, kf0, s0, 0, 0, 0);
            s1 = __builtin_amdgcn_mfma_f32_16x16x32_bf16(qf1, kf1, s1, 0, 0, 0);
        }
        int c0 = k0 + lo, c1 = k0 + 16 + lo;
        float pad0 = (1.0f - pm[c0]) * NEGC;
        float pad1 = (1.0f - pm[c1]) * NEGC;
#pragma unroll
        for (int i = 0; i < 4; i++) {
            int r = qw + hi * 4 + i;
            float a0 = s0[i] * scale + pad0; if (c0 > r) a0 = NEGC;
            float a1 = s1[i] * scale + pad1; if (c1 > r) a1 = NEGC;
            float* pr = Ph + (size_t)r * 1024 + k0;
            pr[lo] = __expf(a0) * invl[i];
            pr[16 + lo] = __expf(a1) * invl[i];
        }
    }
    // zero tail beyond this wave's causal bound
    for (int c = (ktw + 1) * 32 + lo * 4; c < 1024; c += 64) {
#pragma unroll
        for (int i = 0; i < 4; i++) {
            f32x4 z = {};
            *(f32x4*)(Ph + (size_t)(qw + hi * 4 + i) * 1024 + c) = z;
        }
    }
}

// ---------------------------------------------------------------- layernorm (wave per row)
__global__ __launch_bounds__(256) void ln_kernel(
    const float* __restrict__ Y, const float* __restrict__ g, const float* __restrict__ bta,
    float* __restrict__ out)
{
    int row = blockIdx.x * 4 + (threadIdx.x >> 6);
    int l = threadIdx.x & 63;
    const float* yr = Y + (size_t)row * 768;
    f32x4 v0 = *(const f32x4*)(yr + l * 4);
    f32x4 v1 = *(const f32x4*)(yr + 256 + l * 4);
    f32x4 v2 = *(const f32x4*)(yr + 512 + l * 4);
    float s = v0[0] + v0[1] + v0[2] + v0[3] + v1[0] + v1[1] + v1[2] + v1[3]
            + v2[0] + v2[1] + v2[2] + v2[3];
#pragma unroll
    for (int m = 1; m < 64; m <<= 1) s += __shfl_xor(s, m);
    float mu = s * (1.0f / 768.0f);
    float ss = 0.0f;
#pragma unroll
    for (int j = 0; j < 4; j++) {
        float d0 = v0[j] - mu, d1 = v1[j] - mu, d2 = v2[j] - mu;
        ss += d0 * d0 + d1 * d1 + d2 * d2;
    }
#pragma unroll
    for (int m = 1; m < 64; m <<= 1) ss += __shfl_xor(ss, m);
    float r = rsqrtf(ss * (1.0f / 768.0f) + 1e-12f);
    float* orow = out + (size_t)row * 768;
#pragma unroll
    for (int c = 0; c < 3; c++) {
        f32x4 v = (c == 0) ? v0 : ((c == 1) ? v1 : v2);
        int col = c * 256 + l * 4;
        f32x4 gg = *(const f32x4*)(g + col);
        f32x4 bb = *(const f32x4*)(bta + col);
        f32x4 o;
#pragma unroll
        for (int j = 0; j < 4; j++) o[j] = (v[j] - mu) * r * gg[j] + bb[j];
        *(f32x4*)(orow + col) = o;
    }
}

// ---------------------------------------------------------------- launch
extern "C" void kernel_launch(void* const* d_in, const int* in_sizes, int n_in,
                              void* d_out, int out_size, void* d_ws, size_t ws_size,
                              hipStream_t stream)
{
    const float* emb   = (const float*)d_in[0];
    const float* pmask = (const float*)d_in[1];
    const float* wq = (const float*)d_in[2];  const float* bq = (const float*)d_in[3];
    const float* wk = (const float*)d_in[4];  const float* bk = (const float*)d_in[5];
    const float* wv = (const float*)d_in[6];  const float* bv = (const float*)d_in[7];
    const float* wo = (const float*)d_in[8];  const float* bo = (const float*)d_in[9];
    const float* lng = (const float*)d_in[10]; const float* lnb = (const float*)d_in[11];

    __bf16* Xb   = (__bf16*)d_ws;            // 4096*768
    __bf16* Wall = Xb + 4096 * 768;          // 4*768*768  [Wq|Wk|Wv|Wo]
    __bf16* Qb   = Wall + 4 * 589824;
    __bf16* Kb   = Qb + 3145728;
    __bf16* Vb   = Kb + 3145728;
    __bf16* Cb   = Vb + 3145728;
    float*  Yf   = (float*)(Cb + 3145728);   // 4096*768 f32

    float* normed = (float*)d_out;
    float* probs  = normed + (size_t)4096 * 768;

    cvt_bf16<<<1536, 256, 0, stream>>>(emb, Xb, 393216);
    cvt_w4<<<1152, 256, 0, stream>>>(wq, wk, wv, wo, Wall);

    gemm128<0><<<dim3(32, 18), 256, 0, stream>>>(Xb, Wall, bq, bk, bv, Qb, Kb, Vb, nullptr, nullptr);
    attn_kernel<<<dim3(48, 16), 256, 0, stream>>>(Qb, Kb, Vb, pmask, probs, Cb);
    gemm128<1><<<dim3(32, 6), 256, 0, stream>>>(Cb, Wall + 3 * 589824, bo, nullptr, nullptr,
                                                nullptr, nullptr, nullptr, emb, Yf);
    ln_kernel<<<1024, 256, 0, stream>>>(Yf, lng, lnb, normed);
}

// Round 4
// 128.087 us; speedup vs baseline: 2.2571x; 1.2804x over previous
//
#include <hip/hip_runtime.h>
#include <hip/hip_bf16.h>

typedef __bf16 bf16x8 __attribute__((ext_vector_type(8)));
typedef float  f32x4  __attribute__((ext_vector_type(4)));

#define NEGC (-10000.0f)
#define GLDS(src, dst) __builtin_amdgcn_global_load_lds(
#undef GLDS

static __device__ __forceinline__ void glds16(const __bf16* src, __bf16* dst) {
    __builtin_amdgcn_global_load_lds((const __attribute__((address_space(1))) unsigned int*)src,
                                     (__attribute__((address_space(3))) unsigned int*)dst, 16, 0, 0);
}

// ---------------------------------------------------------------- cvt f32->bf16 (embeddings)
__global__ __launch_bounds__(256) void cvt_bf16(const float* __restrict__ in,
                                                __bf16* __restrict__ out, int n8) {
    int i = blockIdx.x * 256 + threadIdx.x;
    if (i >= n8) return;
    f32x4 a = *(const f32x4*)(in + (size_t)i * 8);
    f32x4 b = *(const f32x4*)(in + (size_t)i * 8 + 4);
    bf16x8 o;
    o[0] = (__bf16)a[0]; o[1] = (__bf16)a[1]; o[2] = (__bf16)a[2]; o[3] = (__bf16)a[3];
    o[4] = (__bf16)b[0]; o[5] = (__bf16)b[1]; o[6] = (__bf16)b[2]; o[7] = (__bf16)b[3];
    *(bf16x8*)(out + (size_t)i * 8) = o;
}

// ---------------------------------------------------------------- cvt all 4 weight matrices
__global__ __launch_bounds__(256) void cvt_w4(const float* __restrict__ q, const float* __restrict__ k,
                                              const float* __restrict__ v, const float* __restrict__ o,
                                              __bf16* __restrict__ dst) {
    int blk = blockIdx.x;
    int which = blk / 288;
    const float* src = which == 0 ? q : which == 1 ? k : which == 2 ? v : o;
    int i = (blk - which * 288) * 256 + threadIdx.x;
    f32x4 a = *(const f32x4*)(src + (size_t)i * 8);
    f32x4 b = *(const f32x4*)(src + (size_t)i * 8 + 4);
    bf16x8 o8;
    o8[0] = (__bf16)a[0]; o8[1] = (__bf16)a[1]; o8[2] = (__bf16)a[2]; o8[3] = (__bf16)a[3];
    o8[4] = (__bf16)b[0]; o8[5] = (__bf16)b[1]; o8[6] = (__bf16)b[2]; o8[7] = (__bf16)b[3];
    *(bf16x8*)(dst + (size_t)which * 589824 + (size_t)i * 8) = o8;
}

// ---------------------------------------------------------------- m97-structure GEMM (unchanged)
template<int MODE>
__global__ __launch_bounds__(256) void gemm128(
    const __bf16* __restrict__ A, const __bf16* __restrict__ Bw,
    const float* __restrict__ b0, const float* __restrict__ b1, const float* __restrict__ b2,
    __bf16* __restrict__ O0, __bf16* __restrict__ O1, __bf16* __restrict__ O2,
    const float* __restrict__ res, float* __restrict__ Yout)
{
    __shared__ __align__(16) __bf16 As[128 * 32];
    __shared__ __align__(16) __bf16 Bs[128 * 32];
    const int K = 768;
    int tid = threadIdx.x;
    int l = tid & 63, w = tid >> 6;
    int lo = l & 15, hi = l >> 4;
    int m0 = blockIdx.x * 128, n0 = blockIdx.y * 128;
    int wr = w >> 1, wc = w & 1;

    f32x4 acc[4][4] = {};

    int srow = w * 16 + (l >> 2);
    int scol = (l & 3) * 8;
    const __bf16* gA = A + (size_t)(m0 + srow) * K + scol;
    const __bf16* gB = Bw + (size_t)(n0 + srow) * K + scol;
    __bf16* lA = As + w * 512 + l * 8;
    __bf16* lB = Bs + w * 512 + l * 8;

    for (int k0 = 0; k0 < K; k0 += 32) {
        if (k0) __syncthreads();
        glds16(gA + k0, lA);
        glds16(gA + (size_t)64 * K + k0, lA + 2048);
        glds16(gB + k0, lB);
        glds16(gB + (size_t)64 * K + k0, lB + 2048);
        __syncthreads();

        bf16x8 af[4], bfr[4];
#pragma unroll
        for (int mi = 0; mi < 4; mi++)
            af[mi] = *(const bf16x8*)(As + (wr * 64 + mi * 16 + lo) * 32 + hi * 8);
#pragma unroll
        for (int ni = 0; ni < 4; ni++)
            bfr[ni] = *(const bf16x8*)(Bs + (wc * 64 + ni * 16 + lo) * 32 + hi * 8);
#pragma unroll
        for (int mi = 0; mi < 4; mi++)
#pragma unroll
            for (int ni = 0; ni < 4; ni++)
                acc[mi][ni] = __builtin_amdgcn_mfma_f32_16x16x32_bf16(af[mi], bfr[ni], acc[mi][ni], 0, 0, 0);
    }

    if constexpr (MODE == 0) {
        int which = n0 / 768;
        const float* bias = which == 0 ? b0 : (which == 1 ? b1 : b2);
        __bf16* O = which == 0 ? O0 : (which == 1 ? O1 : O2);
        int nbase = n0 - which * 768;
#pragma unroll
        for (int mi = 0; mi < 4; mi++)
#pragma unroll
            for (int ni = 0; ni < 4; ni++) {
                int within = nbase + wc * 64 + ni * 16 + lo;
                float bv = bias[within];
                int h = within >> 6, d = within & 63;
#pragma unroll
                for (int i = 0; i < 4; i++) {
                    int m = m0 + wr * 64 + mi * 16 + hi * 4 + i;
                    int bb = m >> 10, s = m & 1023;
                    O[(size_t)((bb * 12 + h) * 1024 + s) * 64 + d] = (__bf16)(acc[mi][ni][i] + bv);
                }
            }
    } else {
#pragma unroll
        for (int mi = 0; mi < 4; mi++)
#pragma unroll
            for (int ni = 0; ni < 4; ni++) {
                int n = n0 + wc * 64 + ni * 16 + lo;
                float bv = b0[n];
#pragma unroll
                for (int i = 0; i < 4; i++) {
                    int m = m0 + wr * 64 + mi * 16 + hi * 4 + i;
                    size_t idx = (size_t)m * 768 + n;
                    Yout[idx] = acc[mi][ni][i] + bv + res[idx];
                }
            }
    }
}

// ---------------------------------------------------------------- attention v3
// KVBLK=64, K staged via global_load_lds (dbuf, XOR-swizzled source), V^T dbuf
// reg-load-early/scatter-late. Pass 1: streaming row sums. Pass 2: QK recompute,
// normalized P store + PV. No-max softmax (logits bounded << 87).
__global__ __launch_bounds__(256) void attn_kernel(
    const __bf16* __restrict__ Q, const __bf16* __restrict__ K, const __bf16* __restrict__ V,
    const float* __restrict__ pmask, float* __restrict__ Pout, __bf16* __restrict__ ctx)
{
    int bh = blockIdx.x;
    int b = bh / 12, h = bh - b * 12;
    int y = blockIdx.y;
    int q0 = y * 64;
    int tid = threadIdx.x, l = tid & 63, w = tid >> 6;
    int lo = l & 15, hi = l >> 4;
    int qw = q0 + w * 16;

    const __bf16* Qh = Q + (size_t)bh * 65536;
    const __bf16* Kh = K + (size_t)bh * 65536;
    const __bf16* Vh = V + (size_t)bh * 65536;
    float* Ph = Pout + (size_t)bh * 1048576;
    const float* pm = pmask + b * 1024;

    __shared__ __align__(16) __bf16 Ks[2][64][64];    // 16 KB, dbuf, XOR-swizzled cols
    __shared__ __align__(16) __bf16 vt[2][64][72];    // 18 KB, V^T [d][key], dbuf
    __shared__ __align__(16) __bf16 plds[4][16][72];  // 9 KB, per-wave P tile

    const float scale = 0.036084391824351615f;  // 1/sqrt(768)

    bf16x8 qf0 = *(const bf16x8*)(Qh + (size_t)(qw + lo) * 64 + hi * 8);
    bf16x8 qf1 = *(const bf16x8*)(Qh + (size_t)(qw + lo) * 64 + 32 + hi * 8);

    // K staging: thread t loads row (kt*64 + q*32 + t>>3), colblock (t&7)^((t>>3)&7)
    int srow = tid >> 3;
    int scb  = (tid & 7) ^ (srow & 7);
    __bf16* ldst0 = &Ks[0][0][0] + tid * 8;   // byte tid*16 (linear, wave-uniform+lane*16)

#define STAGE_K(buf, kt)  do {                                             \
        glds16(Kh + (size_t)((kt) * 64 + srow) * 64 + scb * 8,             \
               ldst0 + (buf) * 4096);                                      \
        glds16(Kh + (size_t)((kt) * 64 + 32 + srow) * 64 + scb * 8,        \
               ldst0 + (buf) * 4096 + 2048);                               \
    } while (0)

    // K fragment: logical (row=kn*16+lo, colblock=dh*4+hi) at physical col ^ (row&7)
#define KFRAG(buf, kn, dh) \
    (*(const bf16x8*)(&Ks[buf][(kn) * 16 + lo][(((dh) * 4 + hi) ^ (lo & 7)) * 8]))

    // ---------------- pass 1: row sums (no V, no stores)
    float lsum[4] = {};
    STAGE_K(0, 0);
    __syncthreads();
    for (int kt = 0; kt <= y; kt++) {
        int cur = kt & 1;
        if (kt < y) STAGE_K(cur ^ 1, kt + 1);
        int k0 = kt * 64;
        float pad[4];
#pragma unroll
        for (int kn = 0; kn < 4; kn++) pad[kn] = (1.0f - pm[k0 + kn * 16 + lo]) * NEGC;
        f32x4 s[4] = {};
        __builtin_amdgcn_s_setprio(1);
#pragma unroll
        for (int kn = 0; kn < 4; kn++) {
            s[kn] = __builtin_amdgcn_mfma_f32_16x16x32_bf16(qf0, KFRAG(cur, kn, 0), s[kn], 0, 0, 0);
            s[kn] = __builtin_amdgcn_mfma_f32_16x16x32_bf16(qf1, KFRAG(cur, kn, 1), s[kn], 0, 0, 0);
        }
        __builtin_amdgcn_s_setprio(0);
#pragma unroll
        for (int kn = 0; kn < 4; kn++) {
            int c = k0 + kn * 16 + lo;
#pragma unroll
            for (int i = 0; i < 4; i++) {
                int r = qw + hi * 4 + i;
                float a = s[kn][i] * scale + pad[kn];
                if (c > r) a = NEGC;
                lsum[i] += __expf(a);
            }
        }
        __syncthreads();
    }

    float invl[4];
#pragma unroll
    for (int i = 0; i < 4; i++) {
        float s = lsum[i];
        s += __shfl_xor(s, 1);
        s += __shfl_xor(s, 2);
        s += __shfl_xor(s, 4);
        s += __shfl_xor(s, 8);
        invl[i] = 1.0f / s;
    }

    // ---------------- pass 2: QK recompute, P store, PV
    int vrow = tid >> 2, vcol = (tid & 3) * 16;
    bf16x8 va, vb;
    {   // prologue: K0 + V0 staged, V1 prefetched
        STAGE_K(0, 0);
        const __bf16* vp = Vh + (size_t)vrow * 64 + vcol;
        va = *(const bf16x8*)vp; vb = *(const bf16x8*)(vp + 8);
#pragma unroll
        for (int j = 0; j < 8; j++) vt[0][vcol + j][vrow] = va[j];
#pragma unroll
        for (int j = 0; j < 8; j++) vt[0][vcol + 8 + j][vrow] = vb[j];
        if (y > 0) {
            const __bf16* vp1 = Vh + (size_t)(64 + vrow) * 64 + vcol;
            va = *(const bf16x8*)vp1; vb = *(const bf16x8*)(vp1 + 8);
        }
        __syncthreads();
    }

    f32x4 cacc[4] = {};
    for (int kt = 0; kt <= y; kt++) {
        int cur = kt & 1;
        if (kt < y) STAGE_K(cur ^ 1, kt + 1);
        int k0 = kt * 64;
        float pad[4];
#pragma unroll
        for (int kn = 0; kn < 4; kn++) pad[kn] = (1.0f - pm[k0 + kn * 16 + lo]) * NEGC;
        f32x4 s[4] = {};
        __builtin_amdgcn_s_setprio(1);
#pragma unroll
        for (int kn = 0; kn < 4; kn++) {
            s[kn] = __builtin_amdgcn_mfma_f32_16x16x32_bf16(qf0, KFRAG(cur, kn, 0), s[kn], 0, 0, 0);
            s[kn] = __builtin_amdgcn_mfma_f32_16x16x32_bf16(qf1, KFRAG(cur, kn, 1), s[kn], 0, 0, 0);
        }
        __builtin_amdgcn_s_setprio(0);
#pragma unroll
        for (int kn = 0; kn < 4; kn++) {
            int c = k0 + kn * 16 + lo;
#pragma unroll
            for (int i = 0; i < 4; i++) {
                int r = qw + hi * 4 + i;
                float a = s[kn][i] * scale + pad[kn];
                if (c > r) a = NEGC;
                float p = __expf(a) * invl[i];       // masked -> exactly 0
                Ph[(size_t)r * 1024 + c] = p;
                plds[w][hi * 4 + i][kn * 16 + lo] = (__bf16)p;
            }
        }
        __builtin_amdgcn_s_setprio(1);
#pragma unroll
        for (int ks = 0; ks < 2; ks++) {
            bf16x8 pf = *(const bf16x8*)(&plds[w][lo][ks * 32 + hi * 8]);
#pragma unroll
            for (int dt = 0; dt < 4; dt++) {
                bf16x8 vf = *(const bf16x8*)(&vt[cur][dt * 16 + lo][ks * 32 + hi * 8]);
                cacc[dt] = __builtin_amdgcn_mfma_f32_16x16x32_bf16(pf, vf, cacc[dt], 0, 0, 0);
            }
        }
        __builtin_amdgcn_s_setprio(0);
        if (kt < y) {
#pragma unroll
            for (int j = 0; j < 8; j++) vt[cur ^ 1][vcol + j][vrow] = va[j];
#pragma unroll
            for (int j = 0; j < 8; j++) vt[cur ^ 1][vcol + 8 + j][vrow] = vb[j];
            if (kt + 1 < y) {
                const __bf16* vp = Vh + (size_t)((kt + 2) * 64 + vrow) * 64 + vcol;
                va = *(const bf16x8*)vp; vb = *(const bf16x8*)(vp + 8);
            }
        }
        __syncthreads();
    }

    // ctx store (normalized already): [4096][768] bf16, col = h*64 + d
#pragma unroll
    for (int dt = 0; dt < 4; dt++) {
#pragma unroll
        for (int i = 0; i < 4; i++) {
            int m = b * 1024 + qw + hi * 4 + i;
            int n = h * 64 + dt * 16 + lo;
            ctx[(size_t)m * 768 + n] = (__bf16)cacc[dt][i];
        }
    }

    // zero tail beyond block-causal bound
    for (int c = (y + 1) * 64 + lo * 4; c < 1024; c += 64) {
#pragma unroll
        for (int i = 0; i < 4; i++) {
            f32x4 z = {};
            *(f32x4*)(Ph + (size_t)(qw + hi * 4 + i) * 1024 + c) = z;
        }
    }
#undef STAGE_K
#undef KFRAG
}

// ---------------------------------------------------------------- layernorm (wave per row)
__global__ __launch_bounds__(256) void ln_kernel(
    const float* __restrict__ Y, const float* __restrict__ g, const float* __restrict__ bta,
    float* __restrict__ out)
{
    int row = blockIdx.x * 4 + (threadIdx.x >> 6);
    int l = threadIdx.x & 63;
    const float* yr = Y + (size_t)row * 768;
    f32x4 v0 = *(const f32x4*)(yr + l * 4);
    f32x4 v1 = *(const f32x4*)(yr + 256 + l * 4);
    f32x4 v2 = *(const f32x4*)(yr + 512 + l * 4);
    float s = v0[0] + v0[1] + v0[2] + v0[3] + v1[0] + v1[1] + v1[2] + v1[3]
            + v2[0] + v2[1] + v2[2] + v2[3];
#pragma unroll
    for (int m = 1; m < 64; m <<= 1) s += __shfl_xor(s, m);
    float mu = s * (1.0f / 768.0f);
    float ss = 0.0f;
#pragma unroll
    for (int j = 0; j < 4; j++) {
        float d0 = v0[j] - mu, d1 = v1[j] - mu, d2 = v2[j] - mu;
        ss += d0 * d0 + d1 * d1 + d2 * d2;
    }
#pragma unroll
    for (int m = 1; m < 64; m <<= 1) ss += __shfl_xor(ss, m);
    float r = rsqrtf(ss * (1.0f / 768.0f) + 1e-12f);
    float* orow = out + (size_t)row * 768;
#pragma unroll
    for (int c = 0; c < 3; c++) {
        f32x4 v = (c == 0) ? v0 : ((c == 1) ? v1 : v2);
        int col = c * 256 + l * 4;
        f32x4 gg = *(const f32x4*)(g + col);
        f32x4 bb = *(const f32x4*)(bta + col);
        f32x4 o;
#pragma unroll
        for (int j = 0; j < 4; j++) o[j] = (v[j] - mu) * r * gg[j] + bb[j];
        *(f32x4*)(orow + col) = o;
    }
}

// ---------------------------------------------------------------- launch
extern "C" void kernel_launch(void* const* d_in, const int* in_sizes, int n_in,
                              void* d_out, int out_size, void* d_ws, size_t ws_size,
                              hipStream_t stream)
{
    const float* emb   = (const float*)d_in[0];
    const float* pmask = (const float*)d_in[1];
    const float* wq = (const float*)d_in[2];  const float* bq = (const float*)d_in[3];
    const float* wk = (const float*)d_in[4];  const float* bk = (const float*)d_in[5];
    const float* wv = (const float*)d_in[6];  const float* bv = (const float*)d_in[7];
    const float* wo = (const float*)d_in[8];  const float* bo = (const float*)d_in[9];
    const float* lng = (const float*)d_in[10]; const float* lnb = (const float*)d_in[11];

    __bf16* Xb   = (__bf16*)d_ws;            // 4096*768
    __bf16* Wall = Xb + 4096 * 768;          // 4*768*768  [Wq|Wk|Wv|Wo]
    __bf16* Qb   = Wall + 4 * 589824;
    __bf16* Kb   = Qb + 3145728;
    __bf16* Vb   = Kb + 3145728;
    __bf16* Cb   = Vb + 3145728;
    float*  Yf   = (float*)(Cb + 3145728);   // 4096*768 f32

    float* normed = (float*)d_out;
    float* probs  = normed + (size_t)4096 * 768;

    cvt_bf16<<<1536, 256, 0, stream>>>(emb, Xb, 393216);
    cvt_w4<<<1152, 256, 0, stream>>>(wq, wk, wv, wo, Wall);

    gemm128<0><<<dim3(32, 18), 256, 0, stream>>>(Xb, Wall, bq, bk, bv, Qb, Kb, Vb, nullptr, nullptr);
    attn_kernel<<<dim3(48, 16), 256, 0, stream>>>(Qb, Kb, Vb, pmask, probs, Cb);
    gemm128<1><<<dim3(32, 6), 256, 0, stream>>>(Cb, Wall + 3 * 589824, bo, nullptr, nullptr,
                                                nullptr, nullptr, nullptr, emb, Yf);
    ln_kernel<<<1024, 256, 0, stream>>>(Yf, lng, lnb, normed);
}